// Round 13
// baseline (126.425 us; speedup 1.0000x reference)
//
#include <hip/hip_runtime.h>

// out[b,p] = sum_{e,f} x[b,i_p,e] * K[f,p,e] * x[b,j_p,f]
//
// R10: R9 + epilogue x_i rows ALSO staged via global_load_lds.
//
// R9 diagnosis: staging fixed (one drain), but the epilogue's 32 scalar fp32
// global loads re-serialized (~8k cy of the 11.5k cy span) — compiler sinks
// register-payload loads to use point. global_load_lds has NO payload reg, so
// it cannot be sunk: ALL 20 stage ops (B 4, A 8, xi 8) go out back-to-back
// under ONE vmcnt(0). Epilogue then reads xi from LDS (~300cy incl 4-way
// bank conflict) instead of 32 serialized HBM/L2 latencies.
//
// LDS 80KB: B hi/lo 16K | A hi/lo 32K (XOR-swizzled, rule #21) | xi fp32 32K.
// MFMA path + numerics bit-identical to R9 (absmax must stay 0.0625).

constexpr int BATCH  = 2048;
constexpr int FIELDS = 32;
constexpr int EMBED  = 64;
constexpr int PAIRS  = FIELDS * (FIELDS - 1) / 2;  // 496

typedef __attribute__((ext_vector_type(8))) short  short8;   // 8 bf16 = 4 VGPR
typedef __attribute__((ext_vector_type(4))) float  f32x4;

constexpr size_t XN      = (size_t)BATCH * FIELDS * EMBED;   // 4,194,304
constexpr size_t KPN     = (size_t)PAIRS * 2 * 4 * 64 * 8;   // 2,031,616
constexpr size_t XH_OFF  = 0;
constexpr size_t XL_OFF  = XH_OFF + XN * 2;
constexpr size_t KPH_OFF = XL_OFF + XN * 2;
constexpr size_t KPL_OFF = KPH_OFF + KPN * 2;
constexpr size_t WS_NEED = KPL_OFF + KPN * 2;                // ~24.9 MB

constexpr int XSPLIT_BLOCKS = (int)(XN / 4 / 256);           // 4096
constexpr int KPACK_BLOCKS  = (int)(PAIRS * 512 / 256);      // 992

__device__ __forceinline__ unsigned short bf16_rne(float f) {
    unsigned int u = __float_as_uint(f);
    u = u + 0x7fffu + ((u >> 16) & 1u);
    return (unsigned short)(u >> 16);
}

// ---- Prep: x-split (blocks [0,4096)) and K-pack (blocks [4096,5088)) ----
__global__ __launch_bounds__(256) void prep_kernel(
    const float* __restrict__ x,
    const float* __restrict__ kern,
    unsigned short* __restrict__ xh,
    unsigned short* __restrict__ xl,
    unsigned short* __restrict__ kph,
    unsigned short* __restrict__ kpl)
{
    const int bid = (int)blockIdx.x;
    const int tid = (int)threadIdx.x;

    if (bid < XSPLIT_BLOCKS) {
        const int idx = bid * 256 + tid;
        const float4 v = ((const float4*)x)[idx];
        const float vv[4] = {v.x, v.y, v.z, v.w};
        unsigned short h[4], l[4];
        #pragma unroll
        for (int j = 0; j < 4; ++j) {
            const unsigned int u = __float_as_uint(vv[j]);
            h[j] = (unsigned short)(u >> 16);
            l[j] = bf16_rne(vv[j] - __uint_as_float(u & 0xffff0000u));
        }
        ((ushort4*)xh)[idx] = make_ushort4(h[0], h[1], h[2], h[3]);
        ((ushort4*)xl)[idx] = make_ushort4(l[0], l[1], l[2], l[3]);
    } else {
        // K -> packed B-fragments: chunk t = ((pair*2 + ks)*4 + nc)*64 + lane,
        // elem jj: f = ks*32 + (lane>>4)*8 + jj, e = nc*16 + (lane&15)
        const int t    = (bid - XSPLIT_BLOCKS) * 256 + tid;  // < PAIRS*512
        const int lane = t & 63;
        const int nc   = (t >> 6) & 3;
        const int ks   = (t >> 8) & 1;
        const int pair = t >> 9;
        const int e    = nc * 16 + (lane & 15);
        const int f0   = ks * 32 + (lane >> 4) * 8;

        short8 h8, l8;
        #pragma unroll
        for (int jj = 0; jj < 8; ++jj) {
            const float v = kern[((size_t)(f0 + jj) * PAIRS + pair) * EMBED + e];
            const unsigned int u = __float_as_uint(v);
            h8[jj] = (short)(u >> 16);
            l8[jj] = (short)bf16_rne(v - __uint_as_float(u & 0xffff0000u));
        }
        *(short8*)(kph + (size_t)t * 8) = h8;
        *(short8*)(kpl + (size_t)t * 8) = l8;
    }
}

// ---- Main: grid = 496*16 p-major; 4 waves; wave = 32 rows x 64 e; LDS-staged ----
// LDS map (ushorts): [0,4096) B_hi | [4096,8192) B_lo | [8192,16384) A_hi
//                    [16384,24576) A_lo | [24576,40960) xi fp32 (32KB)
__global__ __launch_bounds__(256, 2) void opn_mfma_kernel(
    const float* __restrict__ x,
    const unsigned short* __restrict__ xh,
    const unsigned short* __restrict__ xl,
    const unsigned short* __restrict__ kph,
    const unsigned short* __restrict__ kpl,
    float* __restrict__ out)
{
    __shared__ unsigned short smem[40960];  // 80 KB

    const int bid  = (int)blockIdx.x;
    const int p    = bid >> 4;                 // p-major: 16 consecutive bids share p
    const int mt   = bid & 15;                 // 128-row tile
    const int tid  = (int)threadIdx.x;
    const int wave = tid >> 6;
    const int lane = tid & 63;
    const int Mb0  = mt * 128;
    const int Mb   = Mb0 + wave * 32;          // this wave's first batch row
    const int g    = lane >> 4;
    const int c    = lane & 15;

    // pair -> (i, j) per jnp.triu_indices(FIELDS, k=1)
    int i = 0, rem = p;
    while (rem >= FIELDS - 1 - i) { rem -= FIELDS - 1 - i; ++i; }
    const int jf = i + 1 + rem;

    // ---- Stage B (linear; fragment-ordered, pair-contiguous) ----
    #pragma unroll
    for (int k = 0; k < 2; ++k) {
        const int q = tid + 256 * k;
        unsigned short* ldst_h = &smem[(size_t)(k * 256 + wave * 64) * 8];
        unsigned short* ldst_l = &smem[4096 + (size_t)(k * 256 + wave * 64) * 8];
        __builtin_amdgcn_global_load_lds(kph + (size_t)p * 4096 + q * 8, ldst_h, 16, 0, 0);
        __builtin_amdgcn_global_load_lds(kpl + (size_t)p * 4096 + q * 8, ldst_l, 16, 0, 0);
    }

    // ---- Stage A rows [Mb0, Mb0+128), field jf, XOR-swizzled source ----
    #pragma unroll
    for (int k = 0; k < 4; ++k) {
        const int q   = tid + 256 * k;          // [0,1024)
        const int row = q >> 3;
        const int cs  = (q & 7) ^ (row & 7);    // inverse-swizzled source col16
        const size_t goff = ((size_t)(Mb0 + row) * FIELDS + jf) * EMBED + cs * 8;
        unsigned short* ldst_h = &smem[8192  + (size_t)(k * 256 + wave * 64) * 8];
        unsigned short* ldst_l = &smem[16384 + (size_t)(k * 256 + wave * 64) * 8];
        __builtin_amdgcn_global_load_lds(xh + goff, ldst_h, 16, 0, 0);
        __builtin_amdgcn_global_load_lds(xl + goff, ldst_l, 16, 0, 0);
    }

    // ---- Stage xi fp32 rows [Mb0, Mb0+128), field i (epilogue operand) ----
    // 2048 chunks of 16B; chunk q: row = q>>4, 4-float group = q&15
    #pragma unroll
    for (int k = 0; k < 8; ++k) {
        const int q   = tid + 256 * k;          // [0,2048)
        const int row = q >> 4;
        const size_t goff = (size_t)(Mb0 + row) * (FIELDS * EMBED) + (size_t)i * EMBED + (q & 15) * 4;
        unsigned short* ldst = &smem[24576 + (size_t)(k * 256 + wave * 64) * 8];
        __builtin_amdgcn_global_load_lds((const unsigned short*)(x + goff), ldst, 16, 0, 0);
    }

    asm volatile("s_waitcnt vmcnt(0)" ::: "memory");
    __syncthreads();

    // ---- MFMA (identical to R9) ----
    f32x4 acc[2][4];
    #pragma unroll
    for (int mr = 0; mr < 2; ++mr)
        #pragma unroll
        for (int nc = 0; nc < 4; ++nc)
            acc[mr][nc] = (f32x4){0.f, 0.f, 0.f, 0.f};

    #pragma unroll
    for (int ks = 0; ks < 2; ++ks) {
        short8 ah[2], al[2];
        #pragma unroll
        for (int mr = 0; mr < 2; ++mr) {
            const int rl = wave * 32 + mr * 16 + c;            // row within block tile
            const int ch = rl * 8 + ((ks * 4 + g) ^ (rl & 7)); // swizzled chunk
            ah[mr] = *(const short8*)&smem[8192  + (size_t)ch * 8];
            al[mr] = *(const short8*)&smem[16384 + (size_t)ch * 8];
        }
        short8 bh[4], bl[4];
        #pragma unroll
        for (int nc = 0; nc < 4; ++nc) {
            const int off = ((ks * 4 + nc) * 64 + lane) * 8;
            bh[nc] = *(const short8*)&smem[off];
            bl[nc] = *(const short8*)&smem[4096 + off];
        }
        #pragma unroll
        for (int mr = 0; mr < 2; ++mr)
            #pragma unroll
            for (int nc = 0; nc < 4; ++nc) {
                acc[mr][nc] = __builtin_amdgcn_mfma_f32_16x16x32_bf16(ah[mr], bh[nc], acc[mr][nc], 0, 0, 0);
                acc[mr][nc] = __builtin_amdgcn_mfma_f32_16x16x32_bf16(ah[mr], bl[nc], acc[mr][nc], 0, 0, 0);
                acc[mr][nc] = __builtin_amdgcn_mfma_f32_16x16x32_bf16(al[mr], bh[nc], acc[mr][nc], 0, 0, 0);
            }
    }

    // ---- Epilogue: xi from LDS; math identical to R8/R9 ----
    const float* fxi = (const float*)&smem[24576];
    float z[2][4];
    #pragma unroll
    for (int mr = 0; mr < 2; ++mr)
        #pragma unroll
        for (int t = 0; t < 4; ++t)
            z[mr][t] = 0.f;

    #pragma unroll
    for (int mr = 0; mr < 2; ++mr)
        #pragma unroll
        for (int t = 0; t < 4; ++t) {
            const int rl = wave * 32 + mr * 16 + 4 * g + t;    // row within block tile
            #pragma unroll
            for (int nc = 0; nc < 4; ++nc)
                z[mr][t] = fmaf(acc[mr][nc][t], fxi[rl * 64 + nc * 16 + c], z[mr][t]);
        }

    #pragma unroll
    for (int mask = 1; mask < 16; mask <<= 1)
        #pragma unroll
        for (int mr = 0; mr < 2; ++mr)
            #pragma unroll
            for (int t = 0; t < 4; ++t)
                z[mr][t] += __shfl_xor(z[mr][t], mask, 64);

    if (c < 4) {  // lane c==t writes rows {Mb + mr*16 + 4g + t}
        const int t = c;
        #pragma unroll
        for (int mr = 0; mr < 2; ++mr) {
            const int row = Mb + mr * 16 + 4 * g + t;
            out[(size_t)row * PAIRS + p] = z[mr][t];
        }
    }
}

// ---- fp32 VALU fallback (only if ws too small) ----
__global__ __launch_bounds__(64) void opn_fp32_kernel(
    const float* __restrict__ x,
    const float* __restrict__ kern,
    float* __restrict__ out)
{
    const int bid   = (int)blockIdx.x;
    const int p     = bid >> 5;
    const int btile = bid & 31;
    const int lane  = (int)threadIdx.x;
    const int b     = btile * 64 + lane;

    int i = 0, rem = p;
    while (rem >= FIELDS - 1 - i) { rem -= FIELDS - 1 - i; ++i; }
    const int j = i + 1 + rem;

    const float* xrow_i = x + (size_t)b * (FIELDS * EMBED) + i * EMBED;
    const float* xrow_j = x + (size_t)b * (FIELDS * EMBED) + j * EMBED;
    const float* kp     = kern + (size_t)p * EMBED;

    float acc[EMBED];
    #pragma unroll
    for (int e = 0; e < EMBED; ++e) acc[e] = 0.0f;

    const float4* xj4 = (const float4*)xrow_j;
    #pragma unroll 2
    for (int f4 = 0; f4 < EMBED / 4; ++f4) {
        const float4 v = xj4[f4];
        const float xjf[4] = {v.x, v.y, v.z, v.w};
        #pragma unroll
        for (int s = 0; s < 4; ++s) {
            const float* kf = kp + (size_t)(f4 * 4 + s) * (PAIRS * EMBED);
            #pragma unroll
            for (int e = 0; e < EMBED; ++e)
                acc[e] = fmaf(xjf[s], kf[e], acc[e]);
        }
    }

    float r = 0.0f;
    const float4* xi4 = (const float4*)xrow_i;
    #pragma unroll
    for (int e4 = 0; e4 < EMBED / 4; ++e4) {
        const float4 u = xi4[e4];
        r = fmaf(u.x, acc[e4 * 4 + 0], r);
        r = fmaf(u.y, acc[e4 * 4 + 1], r);
        r = fmaf(u.z, acc[e4 * 4 + 2], r);
        r = fmaf(u.w, acc[e4 * 4 + 3], r);
    }
    out[(size_t)b * PAIRS + p] = r;
}

extern "C" void kernel_launch(void* const* d_in, const int* in_sizes, int n_in,
                              void* d_out, int out_size, void* d_ws, size_t ws_size,
                              hipStream_t stream) {
    const float* x    = (const float*)d_in[0];
    const float* kern = (const float*)d_in[1];
    float*       out  = (float*)d_out;

    if (ws_size < WS_NEED) {
        opn_fp32_kernel<<<dim3(PAIRS * 32), dim3(64), 0, stream>>>(x, kern, out);
        return;
    }

    char* ws = (char*)d_ws;
    unsigned short* xhi = (unsigned short*)(ws + XH_OFF);
    unsigned short* xlo = (unsigned short*)(ws + XL_OFF);
    unsigned short* kph = (unsigned short*)(ws + KPH_OFF);
    unsigned short* kpl = (unsigned short*)(ws + KPL_OFF);

    prep_kernel<<<dim3(XSPLIT_BLOCKS + KPACK_BLOCKS), dim3(256), 0, stream>>>(
        x, kern, xhi, xlo, kph, kpl);
    opn_mfma_kernel<<<dim3(PAIRS * 16), dim3(256), 0, stream>>>(
        x, xhi, xlo, kph, kpl, out);
}

// Round 14
// 119.441 us; speedup vs baseline: 1.0585x; 1.0585x over previous
//
#include <hip/hip_runtime.h>

// out[b,p] = sum_{e,f} x[b,i_p,e] * K[f,p,e] * x[b,j_p,f]
//
// R11: R9's 48KB-LDS structure + R10's LDS-epilogue, reconciled by RECYCLING
// the A-region for xi after the fragment ds_reads complete.
//
//   stage B+A (12 gload_lds) -> drain -> barrier
//   ds_read ALL A/B fragments (12 x b128) -> barrier (A region now dead)
//   issue xi stage (8 gload_lds into A region)  [sched_barrier pins issue]
//   48 register-only MFMAs (overlap xi flight) -> drain -> barrier
//   epilogue reads xi from LDS (fp32, bit-identical math) -> shfl -> store
//
// R10 lesson: 80KB LDS cost 3->2 blocks/CU and erased the span win. This keeps
// 48KB (3 blocks/CU) AND the single-drain epilogue.

constexpr int BATCH  = 2048;
constexpr int FIELDS = 32;
constexpr int EMBED  = 64;
constexpr int PAIRS  = FIELDS * (FIELDS - 1) / 2;  // 496

typedef __attribute__((ext_vector_type(8))) short  short8;   // 8 bf16 = 4 VGPR
typedef __attribute__((ext_vector_type(4))) float  f32x4;

constexpr size_t XN      = (size_t)BATCH * FIELDS * EMBED;   // 4,194,304
constexpr size_t KPN     = (size_t)PAIRS * 2 * 4 * 64 * 8;   // 2,031,616
constexpr size_t XH_OFF  = 0;
constexpr size_t XL_OFF  = XH_OFF + XN * 2;
constexpr size_t KPH_OFF = XL_OFF + XN * 2;
constexpr size_t KPL_OFF = KPH_OFF + KPN * 2;
constexpr size_t WS_NEED = KPL_OFF + KPN * 2;                // ~24.9 MB

constexpr int XSPLIT_BLOCKS = (int)(XN / 4 / 256);           // 4096
constexpr int KPACK_BLOCKS  = (int)(PAIRS * 512 / 256);      // 992

__device__ __forceinline__ unsigned short bf16_rne(float f) {
    unsigned int u = __float_as_uint(f);
    u = u + 0x7fffu + ((u >> 16) & 1u);
    return (unsigned short)(u >> 16);
}

// ---- Prep: x-split (blocks [0,4096)) and K-pack (blocks [4096,5088)) ----
__global__ __launch_bounds__(256) void prep_kernel(
    const float* __restrict__ x,
    const float* __restrict__ kern,
    unsigned short* __restrict__ xh,
    unsigned short* __restrict__ xl,
    unsigned short* __restrict__ kph,
    unsigned short* __restrict__ kpl)
{
    const int bid = (int)blockIdx.x;
    const int tid = (int)threadIdx.x;

    if (bid < XSPLIT_BLOCKS) {
        const int idx = bid * 256 + tid;
        const float4 v = ((const float4*)x)[idx];
        const float vv[4] = {v.x, v.y, v.z, v.w};
        unsigned short h[4], l[4];
        #pragma unroll
        for (int j = 0; j < 4; ++j) {
            const unsigned int u = __float_as_uint(vv[j]);
            h[j] = (unsigned short)(u >> 16);
            l[j] = bf16_rne(vv[j] - __uint_as_float(u & 0xffff0000u));
        }
        ((ushort4*)xh)[idx] = make_ushort4(h[0], h[1], h[2], h[3]);
        ((ushort4*)xl)[idx] = make_ushort4(l[0], l[1], l[2], l[3]);
    } else {
        // K -> packed B-fragments: chunk t = ((pair*2 + ks)*4 + nc)*64 + lane,
        // elem jj: f = ks*32 + (lane>>4)*8 + jj, e = nc*16 + (lane&15)
        const int t    = (bid - XSPLIT_BLOCKS) * 256 + tid;  // < PAIRS*512
        const int lane = t & 63;
        const int nc   = (t >> 6) & 3;
        const int ks   = (t >> 8) & 1;
        const int pair = t >> 9;
        const int e    = nc * 16 + (lane & 15);
        const int f0   = ks * 32 + (lane >> 4) * 8;

        short8 h8, l8;
        #pragma unroll
        for (int jj = 0; jj < 8; ++jj) {
            const float v = kern[((size_t)(f0 + jj) * PAIRS + pair) * EMBED + e];
            const unsigned int u = __float_as_uint(v);
            h8[jj] = (short)(u >> 16);
            l8[jj] = (short)bf16_rne(v - __uint_as_float(u & 0xffff0000u));
        }
        *(short8*)(kph + (size_t)t * 8) = h8;
        *(short8*)(kpl + (size_t)t * 8) = l8;
    }
}

// ---- Main: grid = 496*16 p-major; 4 waves; wave = 32 rows x 64 e ----
// LDS map (ushorts): [0,4096) B_hi | [4096,8192) B_lo
//                    [8192,24576) A_hi/A_lo, later RECYCLED as xi fp32 (32KB)
__global__ __launch_bounds__(256, 3) void opn_mfma_kernel(
    const float* __restrict__ x,
    const unsigned short* __restrict__ xh,
    const unsigned short* __restrict__ xl,
    const unsigned short* __restrict__ kph,
    const unsigned short* __restrict__ kpl,
    float* __restrict__ out)
{
    __shared__ unsigned short smem[24576];  // 48 KB

    const int bid  = (int)blockIdx.x;
    const int p    = bid >> 4;                 // p-major: 16 consecutive bids share p
    const int mt   = bid & 15;                 // 128-row tile
    const int tid  = (int)threadIdx.x;
    const int wave = tid >> 6;
    const int lane = tid & 63;
    const int Mb0  = mt * 128;
    const int Mb   = Mb0 + wave * 32;          // this wave's first batch row
    const int g    = lane >> 4;
    const int c    = lane & 15;

    // pair -> (i, j) per jnp.triu_indices(FIELDS, k=1)
    int i = 0, rem = p;
    while (rem >= FIELDS - 1 - i) { rem -= FIELDS - 1 - i; ++i; }
    const int jf = i + 1 + rem;

    // ---- Stage B (linear; fragment-ordered, pair-contiguous) ----
    #pragma unroll
    for (int k = 0; k < 2; ++k) {
        const int q = tid + 256 * k;
        unsigned short* ldst_h = &smem[(size_t)(k * 256 + wave * 64) * 8];
        unsigned short* ldst_l = &smem[4096 + (size_t)(k * 256 + wave * 64) * 8];
        __builtin_amdgcn_global_load_lds(kph + (size_t)p * 4096 + q * 8, ldst_h, 16, 0, 0);
        __builtin_amdgcn_global_load_lds(kpl + (size_t)p * 4096 + q * 8, ldst_l, 16, 0, 0);
    }

    // ---- Stage A rows [Mb0, Mb0+128), field jf, XOR-swizzled source ----
    #pragma unroll
    for (int k = 0; k < 4; ++k) {
        const int q   = tid + 256 * k;          // [0,1024)
        const int row = q >> 3;
        const int cs  = (q & 7) ^ (row & 7);    // inverse-swizzled source col16
        const size_t goff = ((size_t)(Mb0 + row) * FIELDS + jf) * EMBED + cs * 8;
        unsigned short* ldst_h = &smem[8192  + (size_t)(k * 256 + wave * 64) * 8];
        unsigned short* ldst_l = &smem[16384 + (size_t)(k * 256 + wave * 64) * 8];
        __builtin_amdgcn_global_load_lds(xh + goff, ldst_h, 16, 0, 0);
        __builtin_amdgcn_global_load_lds(xl + goff, ldst_l, 16, 0, 0);
    }

    asm volatile("s_waitcnt vmcnt(0)" ::: "memory");
    __syncthreads();

    // ---- Hoist ALL fragment ds_reads (A region dead afterwards) ----
    short8 ah[2][2], al[2][2];  // [mr][ks]
    #pragma unroll
    for (int mr = 0; mr < 2; ++mr) {
        const int rl = wave * 32 + mr * 16 + c;            // row within block tile
        #pragma unroll
        for (int ks = 0; ks < 2; ++ks) {
            const int ch = rl * 8 + ((ks * 4 + g) ^ (rl & 7)); // swizzled chunk
            ah[mr][ks] = *(const short8*)&smem[8192  + (size_t)ch * 8];
            al[mr][ks] = *(const short8*)&smem[16384 + (size_t)ch * 8];
        }
    }
    short8 bh[2][4], bl[2][4];  // [ks][nc]
    #pragma unroll
    for (int ks = 0; ks < 2; ++ks)
        #pragma unroll
        for (int nc = 0; nc < 4; ++nc) {
            const int off = ((ks * 4 + nc) * 64 + lane) * 8;
            bh[ks][nc] = *(const short8*)&smem[off];
            bl[ks][nc] = *(const short8*)&smem[4096 + off];
        }

    __syncthreads();  // every wave done reading A region

    // ---- Issue xi stage into recycled A region (fp32, rows [Mb0,Mb0+128)) ----
    #pragma unroll
    for (int k = 0; k < 8; ++k) {
        const int q   = tid + 256 * k;          // [0,2048) chunks of 16B
        const int row = q >> 4;
        const size_t goff = (size_t)(Mb0 + row) * (FIELDS * EMBED) + (size_t)i * EMBED + (q & 15) * 4;
        unsigned short* ldst = &smem[8192 + (size_t)(k * 256 + wave * 64) * 8];
        __builtin_amdgcn_global_load_lds((const unsigned short*)(x + goff), ldst, 16, 0, 0);
    }
    __builtin_amdgcn_sched_barrier(0);  // keep xi issue BEFORE the MFMA block

    // ---- 48 register-only MFMAs (accumulation order identical to R8/R9) ----
    f32x4 acc[2][4];
    #pragma unroll
    for (int mr = 0; mr < 2; ++mr)
        #pragma unroll
        for (int nc = 0; nc < 4; ++nc)
            acc[mr][nc] = (f32x4){0.f, 0.f, 0.f, 0.f};

    #pragma unroll
    for (int ks = 0; ks < 2; ++ks)
        #pragma unroll
        for (int mr = 0; mr < 2; ++mr)
            #pragma unroll
            for (int nc = 0; nc < 4; ++nc) {
                acc[mr][nc] = __builtin_amdgcn_mfma_f32_16x16x32_bf16(ah[mr][ks], bh[ks][nc], acc[mr][nc], 0, 0, 0);
                acc[mr][nc] = __builtin_amdgcn_mfma_f32_16x16x32_bf16(ah[mr][ks], bl[ks][nc], acc[mr][nc], 0, 0, 0);
                acc[mr][nc] = __builtin_amdgcn_mfma_f32_16x16x32_bf16(al[mr][ks], bh[ks][nc], acc[mr][nc], 0, 0, 0);
            }

    asm volatile("s_waitcnt vmcnt(0)" ::: "memory");
    __syncthreads();  // xi landed

    // ---- Epilogue: xi from LDS; math identical to R8/R9/R10 ----
    const float* fxi = (const float*)&smem[8192];
    float z[2][4];
    #pragma unroll
    for (int mr = 0; mr < 2; ++mr)
        #pragma unroll
        for (int t = 0; t < 4; ++t)
            z[mr][t] = 0.f;

    #pragma unroll
    for (int mr = 0; mr < 2; ++mr)
        #pragma unroll
        for (int t = 0; t < 4; ++t) {
            const int rl = wave * 32 + mr * 16 + 4 * g + t;    // row within block tile
            #pragma unroll
            for (int nc = 0; nc < 4; ++nc)
                z[mr][t] = fmaf(acc[mr][nc][t], fxi[rl * 64 + nc * 16 + c], z[mr][t]);
        }

    #pragma unroll
    for (int mask = 1; mask < 16; mask <<= 1)
        #pragma unroll
        for (int mr = 0; mr < 2; ++mr)
            #pragma unroll
            for (int t = 0; t < 4; ++t)
                z[mr][t] += __shfl_xor(z[mr][t], mask, 64);

    if (c < 4) {  // lane c==t writes rows {Mb + mr*16 + 4g + t}
        const int t = c;
        #pragma unroll
        for (int mr = 0; mr < 2; ++mr) {
            const int row = Mb + mr * 16 + 4 * g + t;
            out[(size_t)row * PAIRS + p] = z[mr][t];
        }
    }
}

// ---- fp32 VALU fallback (only if ws too small) ----
__global__ __launch_bounds__(64) void opn_fp32_kernel(
    const float* __restrict__ x,
    const float* __restrict__ kern,
    float* __restrict__ out)
{
    const int bid   = (int)blockIdx.x;
    const int p     = bid >> 5;
    const int btile = bid & 31;
    const int lane  = (int)threadIdx.x;
    const int b     = btile * 64 + lane;

    int i = 0, rem = p;
    while (rem >= FIELDS - 1 - i) { rem -= FIELDS - 1 - i; ++i; }
    const int j = i + 1 + rem;

    const float* xrow_i = x + (size_t)b * (FIELDS * EMBED) + i * EMBED;
    const float* xrow_j = x + (size_t)b * (FIELDS * EMBED) + j * EMBED;
    const float* kp     = kern + (size_t)p * EMBED;

    float acc[EMBED];
    #pragma unroll
    for (int e = 0; e < EMBED; ++e) acc[e] = 0.0f;

    const float4* xj4 = (const float4*)xrow_j;
    #pragma unroll 2
    for (int f4 = 0; f4 < EMBED / 4; ++f4) {
        const float4 v = xj4[f4];
        const float xjf[4] = {v.x, v.y, v.z, v.w};
        #pragma unroll
        for (int s = 0; s < 4; ++s) {
            const float* kf = kp + (size_t)(f4 * 4 + s) * (PAIRS * EMBED);
            #pragma unroll
            for (int e = 0; e < EMBED; ++e)
                acc[e] = fmaf(xjf[s], kf[e], acc[e]);
        }
    }

    float r = 0.0f;
    const float4* xi4 = (const float4*)xrow_i;
    #pragma unroll
    for (int e4 = 0; e4 < EMBED / 4; ++e4) {
        const float4 u = xi4[e4];
        r = fmaf(u.x, acc[e4 * 4 + 0], r);
        r = fmaf(u.y, acc[e4 * 4 + 1], r);
        r = fmaf(u.z, acc[e4 * 4 + 2], r);
        r = fmaf(u.w, acc[e4 * 4 + 3], r);
    }
    out[(size_t)b * PAIRS + p] = r;
}

extern "C" void kernel_launch(void* const* d_in, const int* in_sizes, int n_in,
                              void* d_out, int out_size, void* d_ws, size_t ws_size,
                              hipStream_t stream) {
    const float* x    = (const float*)d_in[0];
    const float* kern = (const float*)d_in[1];
    float*       out  = (float*)d_out;

    if (ws_size < WS_NEED) {
        opn_fp32_kernel<<<dim3(PAIRS * 32), dim3(64), 0, stream>>>(x, kern, out);
        return;
    }

    char* ws = (char*)d_ws;
    unsigned short* xhi = (unsigned short*)(ws + XH_OFF);
    unsigned short* xlo = (unsigned short*)(ws + XL_OFF);
    unsigned short* kph = (unsigned short*)(ws + KPH_OFF);
    unsigned short* kpl = (unsigned short*)(ws + KPL_OFF);

    prep_kernel<<<dim3(XSPLIT_BLOCKS + KPACK_BLOCKS), dim3(256), 0, stream>>>(
        x, kern, xhi, xlo, kph, kpl);
    opn_mfma_kernel<<<dim3(PAIRS * 16), dim3(256), 0, stream>>>(
        x, xhi, xlo, kph, kpl, out);
}